// Round 11
// baseline (69.823 us; speedup 1.0000x reference)
//
#include <hip/hip_runtime.h>
#include <hip/hip_bf16.h>
#include <math.h>

// B=2, S=160, H=768, C=5 ; M = B*S = 320, N = C*H = 3840, K = H = 768

typedef __attribute__((ext_vector_type(8))) short bf16x8;
typedef __attribute__((ext_vector_type(4))) float f32x4;

__device__ __forceinline__ unsigned short f2bf(float f) {
    union { float f; unsigned u; } v; v.f = f;
    unsigned r = (v.u + 0x7FFFu + ((v.u >> 16) & 1u)) >> 16;
    return (unsigned short)r;
}

// fp32 -> bf16 for A (320x768), Wp, Wa (768x3840 each). 8 elems/thread, exact grid.
__global__ __launch_bounds__(256) void convert_bf16(
    const float* __restrict__ A,
    const float* __restrict__ Wp,
    const float* __restrict__ Wa,
    unsigned short* __restrict__ A_bf,
    unsigned short* __restrict__ Wp_bf,
    unsigned short* __restrict__ Wa_bf)
{
    const int NA = 320 * 768 / 8;      // 30720 groups
    const int NW = 768 * 3840 / 8;     // 368640 groups
    int i = blockIdx.x * 256 + threadIdx.x;   // < NA + 2*NW = 768000
    const float* src; unsigned short* dst; int off;
    if (i < NA)            { src = A;  dst = A_bf;  off = i; }
    else if (i < NA + NW)  { src = Wp; dst = Wp_bf; off = i - NA; }
    else                   { src = Wa; dst = Wa_bf; off = i - NA - NW; }
    float4 v0 = *reinterpret_cast<const float4*>(src + (size_t)off * 8);
    float4 v1 = *reinterpret_cast<const float4*>(src + (size_t)off * 8 + 4);
    bf16x8 o;
    o[0] = f2bf(v0.x); o[1] = f2bf(v0.y); o[2] = f2bf(v0.z); o[3] = f2bf(v0.w);
    o[4] = f2bf(v1.x); o[5] = f2bf(v1.y); o[6] = f2bf(v1.z); o[7] = f2bf(v1.w);
    *reinterpret_cast<bf16x8*>(dst + (size_t)off * 8) = o;
}

// 64x64 tile, BK=64, 4 waves x (2x2 fragments x2 k-blocks) of mfma_16x16x32_bf16.
// Epilogue stores clamped tanh(acc+bias) for the tanh-addition identity downstream.
__global__ __launch_bounds__(256) void proj_gemm_bf16(
    const unsigned short* __restrict__ A_bf,   // [320][768]
    const unsigned short* __restrict__ Wp_bf,  // [768][3840]
    const float* __restrict__ bp,
    const unsigned short* __restrict__ Wa_bf,
    const float* __restrict__ ba,
    float* __restrict__ hp,                    // [320][3840] tanh(proj)
    float* __restrict__ ha)
{
    const int which = blockIdx.z;
    const unsigned short* W = which ? Wa_bf : Wp_bf;
    const float* bias       = which ? ba : bp;
    float* out              = which ? ha : hp;

    const int n0 = blockIdx.x * 64;
    const int m0 = blockIdx.y * 64;
    const int tid  = threadIdx.x;
    const int lane = tid & 63;
    const int w    = tid >> 6;

    __shared__ __attribute__((aligned(16))) unsigned short As[64][72]; // [m][k] pad
    __shared__ __attribute__((aligned(16))) unsigned short Bs[64][72]; // [n][k] pad

    f32x4 acc[2][2] = {};

    const int am = tid >> 2;
    const int ak = (tid & 3) * 16;
    const unsigned short* Arow = A_bf + (size_t)(m0 + am) * 768 + ak;

    const int nb = tid & 63;
    const int kt = (tid >> 6) * 16;
    const unsigned short* Wbase = W + (size_t)kt * 3840 + n0 + nb;

    const int wm = (w & 1) * 32;
    const int wn = (w >> 1) * 32;
    const int fr = lane & 15;
    const int fk = (lane >> 4) * 8;

    for (int k0 = 0; k0 < 768; k0 += 64) {
        bf16x8 a0 = *reinterpret_cast<const bf16x8*>(Arow + k0);
        bf16x8 a1 = *reinterpret_cast<const bf16x8*>(Arow + k0 + 8);
        unsigned short bv[16];
        const unsigned short* wp = Wbase + (size_t)k0 * 3840;
        #pragma unroll
        for (int j = 0; j < 16; ++j) bv[j] = wp[(size_t)j * 3840];

        __syncthreads();

        *reinterpret_cast<bf16x8*>(&As[am][ak])     = a0;
        *reinterpret_cast<bf16x8*>(&As[am][ak + 8]) = a1;
        bf16x8 b0, b1;
        #pragma unroll
        for (int j = 0; j < 8; ++j) { b0[j] = (short)bv[j]; b1[j] = (short)bv[8 + j]; }
        *reinterpret_cast<bf16x8*>(&Bs[nb][kt])     = b0;
        *reinterpret_cast<bf16x8*>(&Bs[nb][kt + 8]) = b1;

        __syncthreads();

        #pragma unroll
        for (int kk = 0; kk < 2; ++kk) {
            const int kc = kk * 32 + fk;
            bf16x8 af0 = *reinterpret_cast<const bf16x8*>(&As[wm + fr][kc]);
            bf16x8 af1 = *reinterpret_cast<const bf16x8*>(&As[wm + 16 + fr][kc]);
            bf16x8 bg0 = *reinterpret_cast<const bf16x8*>(&Bs[wn + fr][kc]);
            bf16x8 bg1 = *reinterpret_cast<const bf16x8*>(&Bs[wn + 16 + fr][kc]);
            acc[0][0] = __builtin_amdgcn_mfma_f32_16x16x32_bf16(af0, bg0, acc[0][0], 0, 0, 0);
            acc[0][1] = __builtin_amdgcn_mfma_f32_16x16x32_bf16(af0, bg1, acc[0][1], 0, 0, 0);
            acc[1][0] = __builtin_amdgcn_mfma_f32_16x16x32_bf16(af1, bg0, acc[1][0], 0, 0, 0);
            acc[1][1] = __builtin_amdgcn_mfma_f32_16x16x32_bf16(af1, bg1, acc[1][1], 0, 0, 0);
        }
    }

    // C/D layout: col = lane&15, row = (lane>>4)*4 + reg
    #pragma unroll
    for (int j = 0; j < 2; ++j) {
        const int col = n0 + wn + j * 16 + fr;
        const float bb = bias[col];
        #pragma unroll
        for (int i = 0; i < 2; ++i) {
            #pragma unroll
            for (int r = 0; r < 4; ++r) {
                const int row = m0 + wm + i * 16 + (lane >> 4) * 4 + r;
                float t = tanhf(acc[i][j][r] + bb);
                t = __builtin_amdgcn_fmed3f(t, -0.999999f, 0.999999f);
                out[(size_t)row * 3840 + col] = t;
            }
        }
    }
}

// partial[kq][b,p,c,a] = sum_{h in 96-slice kq} ((tp+ta)/(1+tp*ta))*w  (exact identity)
// 32x32 (p,a) tile, 512 threads (8 waves), 2 outputs per thread (2p x 1a).
// Same LDS as the 256-thread version -> LDS cap now 4 blocks x 8 waves = 32 waves/CU.
__global__ __launch_bounds__(512) void scores_partial(
    const float* __restrict__ tp_g,  // [320, 3840]  tanh(hp)
    const float* __restrict__ ta_g,  // [320, 3840]  tanh(ha)
    const float* __restrict__ w_out, // [768]
    float* __restrict__ part_s)      // [8][256000]
{
    const int at0 = blockIdx.x * 32;
    const int pt0 = blockIdx.y * 32;
    const int z   = blockIdx.z;      // 0..79
    const int bc  = z >> 3;
    const int kq  = z & 7;           // 96-wide h slice
    const int b = bc / 5, c = bc % 5;

    const int tid = threadIdx.x;
    const int tx = tid & 31;         // a index 0..31
    const int ty = tid >> 5;         // p index 0..15

    __shared__ __attribute__((aligned(16))) float w_s[96];
    __shared__ __attribute__((aligned(16))) float hp_s[32][100]; // 96 + 4 pad
    __shared__ __attribute__((aligned(16))) float ha_s[32][100];

    if (tid < 24) {
        *reinterpret_cast<float4*>(&w_s[tid * 4]) =
            *reinterpret_cast<const float4*>(&w_out[kq * 96 + tid * 4]);
    }

    const float* hp_base = tp_g + (size_t)(b * 160 + pt0) * 3840 + c * 768 + kq * 96;
    const float* ha_base = ta_g + (size_t)(b * 160 + at0) * 3840 + c * 768 + kq * 96;

    {   // stage 768 float4 per array (32 rows x 24 f4)
        int f4  = tid;                 // 0..511
        int row = f4 / 24;
        int col = (f4 % 24) * 4;
        *reinterpret_cast<float4*>(&hp_s[row][col]) =
            *reinterpret_cast<const float4*>(&hp_base[(size_t)row * 3840 + col]);
        *reinterpret_cast<float4*>(&ha_s[row][col]) =
            *reinterpret_cast<const float4*>(&ha_base[(size_t)row * 3840 + col]);
        if (tid < 256) {
            f4  = 512 + tid;           // 512..767
            row = f4 / 24;
            col = (f4 % 24) * 4;
            *reinterpret_cast<float4*>(&hp_s[row][col]) =
                *reinterpret_cast<const float4*>(&hp_base[(size_t)row * 3840 + col]);
            *reinterpret_cast<float4*>(&ha_s[row][col]) =
                *reinterpret_cast<const float4*>(&ha_base[(size_t)row * 3840 + col]);
        }
    }
    __syncthreads();

    float acc0 = 0.f, acc1 = 0.f;

    #pragma unroll 6
    for (int j = 0; j < 24; ++j) {
        float4 w4 = *reinterpret_cast<const float4*>(&w_s[j * 4]);
        float4 p0 = *reinterpret_cast<const float4*>(&hp_s[ty     ][j * 4]);
        float4 p1 = *reinterpret_cast<const float4*>(&hp_s[ty + 16][j * 4]);
        float4 a0 = *reinterpret_cast<const float4*>(&ha_s[tx     ][j * 4]);

#define TERM(ACC, P, A, W) \
        { float s_ = (P) + (A); \
          float d_ = fmaf((P), (A), 1.f); \
          ACC = fmaf(s_ * __builtin_amdgcn_rcpf(d_), (W), ACC); }

        TERM(acc0, p0.x, a0.x, w4.x)
        TERM(acc1, p1.x, a0.x, w4.x)
        TERM(acc0, p0.y, a0.y, w4.y)
        TERM(acc1, p1.y, a0.y, w4.y)
        TERM(acc0, p0.z, a0.z, w4.z)
        TERM(acc1, p1.z, a0.z, w4.z)
        TERM(acc0, p0.w, a0.w, w4.w)
        TERM(acc1, p1.w, a0.w, w4.w)
#undef TERM
    }

    float* dst = part_s + (size_t)kq * 256000;
    const int a = at0 + tx;
    {
        const int p = pt0 + ty;
        dst[((size_t)(b * 160 + p) * 5 + c) * 160 + a] = acc0;
    }
    {
        const int p = pt0 + 16 + ty;
        dst[((size_t)(b * 160 + p) * 5 + c) * 160 + a] = acc1;
    }
}

// one wave per (b,p,c) row: sum 8 partials + mask bias -> write scores to d_out,
// then row log-softmax loss; per-block partial -> part[blk] (NO atomics).
__global__ __launch_bounds__(256) void loss_kernel(
    const float* __restrict__ part_s,  // [8][256000]
    const int*  __restrict__ mask,
    const int*  __restrict__ target,
    float* __restrict__ scores_out,    // [256000] (d_out+1)
    float* __restrict__ part)          // [400][2]
{
    const int lane = threadIdx.x & 63;
    const int wid  = threadIdx.x >> 6;
    const int row  = blockIdx.x * 4 + wid;  // 0..1599
    const size_t base = (size_t)row * 160;

    float x0 = 0.f, x1 = 0.f, x2 = 0.f;
    #pragma unroll
    for (int k = 0; k < 8; ++k) {
        const float* ps = part_s + (size_t)k * 256000 + base;
        x0 += ps[lane];
        x1 += ps[lane + 64];
        if (lane < 32) x2 += ps[lane + 128];
    }
    x0 += mask[base + lane] ? 0.f : -1024.f;
    x1 += mask[base + lane + 64] ? 0.f : -1024.f;
    if (lane < 32) x2 += mask[base + lane + 128] ? 0.f : -1024.f;

    scores_out[base + lane] = x0;
    scores_out[base + lane + 64] = x1;
    if (lane < 32) scores_out[base + lane + 128] = x2;

    float x2r = (lane < 32) ? x2 : -INFINITY;

    float m = fmaxf(fmaxf(x0, x1), x2r);
    #pragma unroll
    for (int o = 32; o >= 1; o >>= 1)
        m = fmaxf(m, __shfl_xor(m, o));

    float s = __expf(x0 - m) + __expf(x1 - m) + ((lane < 32) ? __expf(x2 - m) : 0.f);
    #pragma unroll
    for (int o = 32; o >= 1; o >>= 1)
        s += __shfl_xor(s, o);
    float lse = logf(s) + m;

    const int* t = target + base;
    int t0 = t[lane], t1 = t[lane + 64];
    int t2 = (lane < 32) ? t[lane + 128] : 0;
    float pl = (float)t0 * (lse - x0) + (float)t1 * (lse - x1)
             + ((lane < 32 && t2) ? (float)t2 * (lse - x2) : 0.f);
    float pts = (float)(t0 + t1 + t2);
    #pragma unroll
    for (int o = 32; o >= 1; o >>= 1) {
        pl  += __shfl_xor(pl, o);
        pts += __shfl_xor(pts, o);
    }

    __shared__ float sp[4], st[4];
    if (lane == 0) { sp[wid] = pl; st[wid] = pts; }
    __syncthreads();
    if (threadIdx.x == 0) {
        part[blockIdx.x * 2]     = sp[0] + sp[1] + sp[2] + sp[3];
        part[blockIdx.x * 2 + 1] = st[0] + st[1] + st[2] + st[3];
    }
}

// single block: reduce 400 (pl, pts) pairs -> loss
__global__ __launch_bounds__(256) void finalize_kernel(
    const float* __restrict__ part, float* __restrict__ out0)
{
    const int tid = threadIdx.x;
    float pl = 0.f, pts = 0.f;
    for (int i = tid; i < 400; i += 256) {
        pl  += part[i * 2];
        pts += part[i * 2 + 1];
    }
    #pragma unroll
    for (int o = 32; o >= 1; o >>= 1) {
        pl  += __shfl_xor(pl, o);
        pts += __shfl_xor(pts, o);
    }
    __shared__ float sp[4], st[4];
    const int wid = tid >> 6;
    if ((tid & 63) == 0) { sp[wid] = pl; st[wid] = pts; }
    __syncthreads();
    if (tid == 0) {
        float tl = sp[0] + sp[1] + sp[2] + sp[3];
        float tt = st[0] + st[1] + st[2] + st[3];
        out0[0] = tl / (tt + 1e-6f);
    }
}

extern "C" void kernel_launch(void* const* d_in, const int* in_sizes, int n_in,
                              void* d_out, int out_size, void* d_ws, size_t ws_size,
                              hipStream_t stream) {
    const float* seq   = (const float*)d_in[0];
    const float* w_prd = (const float*)d_in[1];
    const float* b_prd = (const float*)d_in[2];
    const float* w_arg = (const float*)d_in[3];
    const float* b_arg = (const float*)d_in[4];
    const float* w_out = (const float*)d_in[5];
    const int*   mask  = (const int*)d_in[6];
    const int*   targ  = (const int*)d_in[7];

    float* out = (float*)d_out;          // out[0]=loss, out+1 = scores [2,160,5,160]

    char* ws = (char*)d_ws;
    float* hp     = (float*)ws;                      // 320*3840 f32   (4915200 B)
    float* ha     = (float*)(ws + 4915200);          // 320*3840 f32
    float* part_s = (float*)(ws + 9830400);          // 8*256000 f32   (8192000 B)
    float* part   = (float*)(ws + 18022400);         // 400*2 f32      (3200 B)
    unsigned short* A_bf  = (unsigned short*)(ws + 18025600);  // 320*768
    unsigned short* Wp_bf = (unsigned short*)(ws + 18517120);  // 768*3840
    unsigned short* Wa_bf = (unsigned short*)(ws + 24415360);  // 768*3840

    convert_bf16<<<3000, 256, 0, stream>>>(seq, w_prd, w_arg, A_bf, Wp_bf, Wa_bf);

    dim3 g1(60, 5, 2);   // N/64, M/64, {prd,arg}
    proj_gemm_bf16<<<g1, 256, 0, stream>>>(A_bf, Wp_bf, b_prd, Wa_bf, b_arg, hp, ha);

    dim3 g2(5, 5, 80);   // a-tiles(32), p-tiles(32), b*c*k8
    scores_partial<<<g2, 512, 0, stream>>>(hp, ha, w_out, part_s);

    loss_kernel<<<400, 256, 0, stream>>>(part_s, mask, targ, out + 1, part);
    finalize_kernel<<<1, 256, 0, stream>>>(part, out);
}

// Round 12
// 50.715 us; speedup vs baseline: 1.3768x; 1.3768x over previous
//
#include <hip/hip_runtime.h>
#include <hip/hip_bf16.h>
#include <math.h>

// B=2, S=160, H=768, C=5 ; M = B*S = 320, N = C*H = 3840, K = H = 768

typedef __attribute__((ext_vector_type(8))) short bf16x8;
typedef __attribute__((ext_vector_type(4))) float f32x4;

__device__ __forceinline__ unsigned short f2bf(float f) {
    union { float f; unsigned u; } v; v.f = f;
    unsigned r = (v.u + 0x7FFFu + ((v.u >> 16) & 1u)) >> 16;
    return (unsigned short)r;
}

// pack two fp32 -> 2xbf16 dword (round-to-nearest, no tie fix: bias 2^-17, fine here)
__device__ __forceinline__ unsigned pack2bf(float lo, float hi) {
    union { float f; unsigned u; } a, b; a.f = lo; b.f = hi;
    return ((a.u + 0x8000u) >> 16) | ((b.u + 0x8000u) & 0xFFFF0000u);
}

// fp32 -> bf16 for A (320x768), Wp, Wa (768x3840 each). 8 elems/thread, exact grid.
__global__ __launch_bounds__(256) void convert_bf16(
    const float* __restrict__ A,
    const float* __restrict__ Wp,
    const float* __restrict__ Wa,
    unsigned short* __restrict__ A_bf,
    unsigned short* __restrict__ Wp_bf,
    unsigned short* __restrict__ Wa_bf)
{
    const int NA = 320 * 768 / 8;      // 30720 groups
    const int NW = 768 * 3840 / 8;     // 368640 groups
    int i = blockIdx.x * 256 + threadIdx.x;   // < NA + 2*NW = 768000
    const float* src; unsigned short* dst; int off;
    if (i < NA)            { src = A;  dst = A_bf;  off = i; }
    else if (i < NA + NW)  { src = Wp; dst = Wp_bf; off = i - NA; }
    else                   { src = Wa; dst = Wa_bf; off = i - NA - NW; }
    float4 v0 = *reinterpret_cast<const float4*>(src + (size_t)off * 8);
    float4 v1 = *reinterpret_cast<const float4*>(src + (size_t)off * 8 + 4);
    bf16x8 o;
    o[0] = f2bf(v0.x); o[1] = f2bf(v0.y); o[2] = f2bf(v0.z); o[3] = f2bf(v0.w);
    o[4] = f2bf(v1.x); o[5] = f2bf(v1.y); o[6] = f2bf(v1.z); o[7] = f2bf(v1.w);
    *reinterpret_cast<bf16x8*>(dst + (size_t)off * 8) = o;
}

// 64x64 tile, BK=64, 4 waves x (2x2 fragments x2 k-blocks) of mfma_16x16x32_bf16.
// Epilogue stores clamped tanh(acc+bias) for the downstream series expansion.
__global__ __launch_bounds__(256) void proj_gemm_bf16(
    const unsigned short* __restrict__ A_bf,   // [320][768]
    const unsigned short* __restrict__ Wp_bf,  // [768][3840]
    const float* __restrict__ bp,
    const unsigned short* __restrict__ Wa_bf,
    const float* __restrict__ ba,
    float* __restrict__ hp,                    // [320][3840] tanh(proj)
    float* __restrict__ ha)
{
    const int which = blockIdx.z;
    const unsigned short* W = which ? Wa_bf : Wp_bf;
    const float* bias       = which ? ba : bp;
    float* out              = which ? ha : hp;

    const int n0 = blockIdx.x * 64;
    const int m0 = blockIdx.y * 64;
    const int tid  = threadIdx.x;
    const int lane = tid & 63;
    const int w    = tid >> 6;

    __shared__ __attribute__((aligned(16))) unsigned short As[64][72]; // [m][k] pad
    __shared__ __attribute__((aligned(16))) unsigned short Bs[64][72]; // [n][k] pad

    f32x4 acc[2][2] = {};

    const int am = tid >> 2;
    const int ak = (tid & 3) * 16;
    const unsigned short* Arow = A_bf + (size_t)(m0 + am) * 768 + ak;

    const int nb = tid & 63;
    const int kt = (tid >> 6) * 16;
    const unsigned short* Wbase = W + (size_t)kt * 3840 + n0 + nb;

    const int wm = (w & 1) * 32;
    const int wn = (w >> 1) * 32;
    const int fr = lane & 15;
    const int fk = (lane >> 4) * 8;

    for (int k0 = 0; k0 < 768; k0 += 64) {
        bf16x8 a0 = *reinterpret_cast<const bf16x8*>(Arow + k0);
        bf16x8 a1 = *reinterpret_cast<const bf16x8*>(Arow + k0 + 8);
        unsigned short bv[16];
        const unsigned short* wp = Wbase + (size_t)k0 * 3840;
        #pragma unroll
        for (int j = 0; j < 16; ++j) bv[j] = wp[(size_t)j * 3840];

        __syncthreads();

        *reinterpret_cast<bf16x8*>(&As[am][ak])     = a0;
        *reinterpret_cast<bf16x8*>(&As[am][ak + 8]) = a1;
        bf16x8 b0, b1;
        #pragma unroll
        for (int j = 0; j < 8; ++j) { b0[j] = (short)bv[j]; b1[j] = (short)bv[8 + j]; }
        *reinterpret_cast<bf16x8*>(&Bs[nb][kt])     = b0;
        *reinterpret_cast<bf16x8*>(&Bs[nb][kt + 8]) = b1;

        __syncthreads();

        #pragma unroll
        for (int kk = 0; kk < 2; ++kk) {
            const int kc = kk * 32 + fk;
            bf16x8 af0 = *reinterpret_cast<const bf16x8*>(&As[wm + fr][kc]);
            bf16x8 af1 = *reinterpret_cast<const bf16x8*>(&As[wm + 16 + fr][kc]);
            bf16x8 bg0 = *reinterpret_cast<const bf16x8*>(&Bs[wn + fr][kc]);
            bf16x8 bg1 = *reinterpret_cast<const bf16x8*>(&Bs[wn + 16 + fr][kc]);
            acc[0][0] = __builtin_amdgcn_mfma_f32_16x16x32_bf16(af0, bg0, acc[0][0], 0, 0, 0);
            acc[0][1] = __builtin_amdgcn_mfma_f32_16x16x32_bf16(af0, bg1, acc[0][1], 0, 0, 0);
            acc[1][0] = __builtin_amdgcn_mfma_f32_16x16x32_bf16(af1, bg0, acc[1][0], 0, 0, 0);
            acc[1][1] = __builtin_amdgcn_mfma_f32_16x16x32_bf16(af1, bg1, acc[1][1], 0, 0, 0);
        }
    }

    // C/D layout: col = lane&15, row = (lane>>4)*4 + reg
    #pragma unroll
    for (int j = 0; j < 2; ++j) {
        const int col = n0 + wn + j * 16 + fr;
        const float bb = bias[col];
        #pragma unroll
        for (int i = 0; i < 2; ++i) {
            #pragma unroll
            for (int r = 0; r < 4; ++r) {
                const int row = m0 + wm + i * 16 + (lane >> 4) * 4 + r;
                float t = tanhf(acc[i][j][r] + bb);
                t = __builtin_amdgcn_fmed3f(t, -0.999999f, 0.999999f);
                out[(size_t)row * 3840 + col] = t;
            }
        }
    }
}

// Series-GEMM scores: score[p,a] = sum_{j=0..7} sum_h tp^j * g_j(ta)
//   g_0 = w*ta ; g_1 = w*(1-ta^2) ; g_{j+1} = -ta*g_j   (truncation err <= |tp*ta|^7)
// One wave (64 thr) per block computes a 32x32 (p,a) tile for one (b,c,hq).
// Powers generated in-register during staging into wave-private ping-pong LDS
// (no barriers); 4x mfma_16x16x32_bf16 per j-step. part_s slab per hq (8).
__global__ __launch_bounds__(64) void scores_mfma(
    const float* __restrict__ tp_g,  // [320][3840] tanh(hp), |t| < 1
    const float* __restrict__ ta_g,  // [320][3840] tanh(ha)
    const float* __restrict__ w_out, // [768]
    float* __restrict__ part_s)      // [8][256000]
{
    const int at0 = blockIdx.x * 32;
    const int pt0 = blockIdx.y * 32;
    const int z   = blockIdx.z;      // 0..79
    const int bc  = z >> 3;
    const int hq  = z & 7;           // 96-wide h slice
    const int b = bc / 5, c = bc % 5;

    const int lane = threadIdx.x;    // 0..63
    const int r    = lane >> 1;      // staging row 0..31
    const int hh   = (lane & 1) * 16;// staging col offset
    const int fr   = lane & 15;
    const int fk   = (lane >> 4) * 8;

    __shared__ __attribute__((aligned(16))) unsigned short Pb[2][32][40];
    __shared__ __attribute__((aligned(16))) unsigned short Gb[2][32][40];

    f32x4 acc[2][2] = {};

    const float* psrc = tp_g + (size_t)(b * 160 + pt0 + r) * 3840 + c * 768 + hq * 96 + hh;
    const float* asrc = ta_g + (size_t)(b * 160 + at0 + r) * 3840 + c * 768 + hq * 96 + hh;
    const float* wsrc = w_out + hq * 96 + hh;

    for (int ch = 0; ch < 3; ++ch) {   // 3 h-chunks of 32
        float tp[16], nta[16], pw[16], gc[16], g1[16];
        {
            float tav[16], wv[16];
#define LD16(arr, ptr) { \
            float4 v_; \
            v_ = *reinterpret_cast<const float4*>((ptr));      arr[0]=v_.x; arr[1]=v_.y; arr[2]=v_.z; arr[3]=v_.w; \
            v_ = *reinterpret_cast<const float4*>((ptr) + 4);  arr[4]=v_.x; arr[5]=v_.y; arr[6]=v_.z; arr[7]=v_.w; \
            v_ = *reinterpret_cast<const float4*>((ptr) + 8);  arr[8]=v_.x; arr[9]=v_.y; arr[10]=v_.z; arr[11]=v_.w; \
            v_ = *reinterpret_cast<const float4*>((ptr) + 12); arr[12]=v_.x; arr[13]=v_.y; arr[14]=v_.z; arr[15]=v_.w; }
            LD16(tp,  psrc + ch * 32)
            LD16(tav, asrc + ch * 32)
            LD16(wv,  wsrc + ch * 32)
#undef LD16
            #pragma unroll
            for (int e = 0; e < 16; ++e) {
                float ta_ = tav[e];
                gc[e]  = wv[e] * ta_;                       // g_0
                g1[e]  = wv[e] * fmaf(-ta_, ta_, 1.f);      // g_1
                nta[e] = -ta_;
                pw[e]  = 1.0f;                              // tp^0
            }
        }

        #pragma unroll
        for (int j = 0; j < 8; ++j) {
            const int pp = j & 1;
            uint4 q;
            q.x = pack2bf(pw[0],  pw[1]);  q.y = pack2bf(pw[2],  pw[3]);
            q.z = pack2bf(pw[4],  pw[5]);  q.w = pack2bf(pw[6],  pw[7]);
            *reinterpret_cast<uint4*>(&Pb[pp][r][hh]) = q;
            q.x = pack2bf(pw[8],  pw[9]);  q.y = pack2bf(pw[10], pw[11]);
            q.z = pack2bf(pw[12], pw[13]); q.w = pack2bf(pw[14], pw[15]);
            *reinterpret_cast<uint4*>(&Pb[pp][r][hh + 8]) = q;
            q.x = pack2bf(gc[0],  gc[1]);  q.y = pack2bf(gc[2],  gc[3]);
            q.z = pack2bf(gc[4],  gc[5]);  q.w = pack2bf(gc[6],  gc[7]);
            *reinterpret_cast<uint4*>(&Gb[pp][r][hh]) = q;
            q.x = pack2bf(gc[8],  gc[9]);  q.y = pack2bf(gc[10], gc[11]);
            q.z = pack2bf(gc[12], gc[13]); q.w = pack2bf(gc[14], gc[15]);
            *reinterpret_cast<uint4*>(&Gb[pp][r][hh + 8]) = q;

            bf16x8 af0 = *reinterpret_cast<const bf16x8*>(&Pb[pp][fr][fk]);
            bf16x8 af1 = *reinterpret_cast<const bf16x8*>(&Pb[pp][16 + fr][fk]);
            bf16x8 bg0 = *reinterpret_cast<const bf16x8*>(&Gb[pp][fr][fk]);
            bf16x8 bg1 = *reinterpret_cast<const bf16x8*>(&Gb[pp][16 + fr][fk]);
            acc[0][0] = __builtin_amdgcn_mfma_f32_16x16x32_bf16(af0, bg0, acc[0][0], 0, 0, 0);
            acc[0][1] = __builtin_amdgcn_mfma_f32_16x16x32_bf16(af0, bg1, acc[0][1], 0, 0, 0);
            acc[1][0] = __builtin_amdgcn_mfma_f32_16x16x32_bf16(af1, bg0, acc[1][0], 0, 0, 0);
            acc[1][1] = __builtin_amdgcn_mfma_f32_16x16x32_bf16(af1, bg1, acc[1][1], 0, 0, 0);

            #pragma unroll
            for (int e = 0; e < 16; ++e) {
                pw[e] *= tp[e];
                gc[e] = (j == 0) ? g1[e] : gc[e] * nta[e];
            }
        }
    }

    // C/D: col(a) = lane&15, row(p) = (lane>>4)*4 + reg
    float* dst = part_s + (size_t)hq * 256000;
    #pragma unroll
    for (int i = 0; i < 2; ++i) {
        #pragma unroll
        for (int jj = 0; jj < 2; ++jj) {
            #pragma unroll
            for (int rr = 0; rr < 4; ++rr) {
                const int p = pt0 + i * 16 + (lane >> 4) * 4 + rr;
                const int a = at0 + jj * 16 + fr;
                dst[((size_t)(b * 160 + p) * 5 + c) * 160 + a] = acc[i][jj][rr];
            }
        }
    }
}

// one wave per (b,p,c) row: sum 8 partials + mask bias -> write scores to d_out,
// then row log-softmax loss; per-block partial -> part[blk] (NO atomics).
__global__ __launch_bounds__(256) void loss_kernel(
    const float* __restrict__ part_s,  // [8][256000]
    const int*  __restrict__ mask,
    const int*  __restrict__ target,
    float* __restrict__ scores_out,    // [256000] (d_out+1)
    float* __restrict__ part)          // [400][2]
{
    const int lane = threadIdx.x & 63;
    const int wid  = threadIdx.x >> 6;
    const int row  = blockIdx.x * 4 + wid;  // 0..1599
    const size_t base = (size_t)row * 160;

    float x0 = 0.f, x1 = 0.f, x2 = 0.f;
    #pragma unroll
    for (int k = 0; k < 8; ++k) {
        const float* ps = part_s + (size_t)k * 256000 + base;
        x0 += ps[lane];
        x1 += ps[lane + 64];
        if (lane < 32) x2 += ps[lane + 128];
    }
    x0 += mask[base + lane] ? 0.f : -1024.f;
    x1 += mask[base + lane + 64] ? 0.f : -1024.f;
    if (lane < 32) x2 += mask[base + lane + 128] ? 0.f : -1024.f;

    scores_out[base + lane] = x0;
    scores_out[base + lane + 64] = x1;
    if (lane < 32) scores_out[base + lane + 128] = x2;

    float x2r = (lane < 32) ? x2 : -INFINITY;

    float m = fmaxf(fmaxf(x0, x1), x2r);
    #pragma unroll
    for (int o = 32; o >= 1; o >>= 1)
        m = fmaxf(m, __shfl_xor(m, o));

    float s = __expf(x0 - m) + __expf(x1 - m) + ((lane < 32) ? __expf(x2 - m) : 0.f);
    #pragma unroll
    for (int o = 32; o >= 1; o >>= 1)
        s += __shfl_xor(s, o);
    float lse = logf(s) + m;

    const int* t = target + base;
    int t0 = t[lane], t1 = t[lane + 64];
    int t2 = (lane < 32) ? t[lane + 128] : 0;
    float pl = (float)t0 * (lse - x0) + (float)t1 * (lse - x1)
             + ((lane < 32 && t2) ? (float)t2 * (lse - x2) : 0.f);
    float pts = (float)(t0 + t1 + t2);
    #pragma unroll
    for (int o = 32; o >= 1; o >>= 1) {
        pl  += __shfl_xor(pl, o);
        pts += __shfl_xor(pts, o);
    }

    __shared__ float sp[4], st[4];
    if (lane == 0) { sp[wid] = pl; st[wid] = pts; }
    __syncthreads();
    if (threadIdx.x == 0) {
        part[blockIdx.x * 2]     = sp[0] + sp[1] + sp[2] + sp[3];
        part[blockIdx.x * 2 + 1] = st[0] + st[1] + st[2] + st[3];
    }
}

// single block: reduce 400 (pl, pts) pairs -> loss
__global__ __launch_bounds__(256) void finalize_kernel(
    const float* __restrict__ part, float* __restrict__ out0)
{
    const int tid = threadIdx.x;
    float pl = 0.f, pts = 0.f;
    for (int i = tid; i < 400; i += 256) {
        pl  += part[i * 2];
        pts += part[i * 2 + 1];
    }
    #pragma unroll
    for (int o = 32; o >= 1; o >>= 1) {
        pl  += __shfl_xor(pl, o);
        pts += __shfl_xor(pts, o);
    }
    __shared__ float sp[4], st[4];
    const int wid = tid >> 6;
    if ((tid & 63) == 0) { sp[wid] = pl; st[wid] = pts; }
    __syncthreads();
    if (tid == 0) {
        float tl = sp[0] + sp[1] + sp[2] + sp[3];
        float tt = st[0] + st[1] + st[2] + st[3];
        out0[0] = tl / (tt + 1e-6f);
    }
}

extern "C" void kernel_launch(void* const* d_in, const int* in_sizes, int n_in,
                              void* d_out, int out_size, void* d_ws, size_t ws_size,
                              hipStream_t stream) {
    const float* seq   = (const float*)d_in[0];
    const float* w_prd = (const float*)d_in[1];
    const float* b_prd = (const float*)d_in[2];
    const float* w_arg = (const float*)d_in[3];
    const float* b_arg = (const float*)d_in[4];
    const float* w_out = (const float*)d_in[5];
    const int*   mask  = (const int*)d_in[6];
    const int*   targ  = (const int*)d_in[7];

    float* out = (float*)d_out;          // out[0]=loss, out+1 = scores [2,160,5,160]

    char* ws = (char*)d_ws;
    float* hp     = (float*)ws;                      // 320*3840 f32   (4915200 B)
    float* ha     = (float*)(ws + 4915200);          // 320*3840 f32
    float* part_s = (float*)(ws + 9830400);          // 8*256000 f32   (8192000 B)
    float* part   = (float*)(ws + 18022400);         // 400*2 f32      (3200 B)
    unsigned short* A_bf  = (unsigned short*)(ws + 18025600);  // 320*768
    unsigned short* Wp_bf = (unsigned short*)(ws + 18517120);  // 768*3840
    unsigned short* Wa_bf = (unsigned short*)(ws + 24415360);  // 768*3840

    convert_bf16<<<3000, 256, 0, stream>>>(seq, w_prd, w_arg, A_bf, Wp_bf, Wa_bf);

    dim3 g1(60, 5, 2);   // N/64, M/64, {prd,arg}
    proj_gemm_bf16<<<g1, 256, 0, stream>>>(A_bf, Wp_bf, b_prd, Wa_bf, b_arg, hp, ha);

    dim3 g2(5, 5, 80);   // a-tiles(32), p-tiles(32), bc*hq
    scores_mfma<<<g2, 64, 0, stream>>>(hp, ha, w_out, part_s);

    loss_kernel<<<400, 256, 0, stream>>>(part_s, mask, targ, out + 1, part);
    finalize_kernel<<<1, 256, 0, stream>>>(part, out);
}